// Round 16
// baseline (92.330 us; speedup 1.0000x reference)
//
#include <hip/hip_runtime.h>
#include <cstdint>
#include <cstddef>

#define B_   32
#define N_   256
#define C_   256
#define DFF_ 1024

typedef unsigned short ushort_t;
typedef __attribute__((ext_vector_type(8))) short bf16x8;
typedef __attribute__((ext_vector_type(4))) float f32x4;

__device__ __forceinline__ ushort_t f2bf(float f) {
    unsigned u = __builtin_bit_cast(unsigned, f);
    u += 0x7FFFu + ((u >> 16) & 1u);
    return (ushort_t)(u >> 16);
}
__device__ __forceinline__ float bf2f(ushort_t b) {
    return __builtin_bit_cast(float, (unsigned)b << 16);
}

// 128B-row swizzle: XOR byte-bits 4-6 with row bits 7-9 -> involution
__device__ __forceinline__ unsigned swz64(unsigned a) {
    return a ^ (((a >> 7) & 7u) << 4);
}

#define GLL(src, dst) __builtin_amdgcn_global_load_lds( \
    (const __attribute__((address_space(1))) void*)(src), \
    (__attribute__((address_space(3))) void*)(dst), 16, 0, 0)

// ======== prep: blocks 0-31 geo, block 32 bnprep, blocks 33-672 wprep ========
__global__ void k_prep(const float* __restrict__ coords,
                       ushort_t* __restrict__ nbr, int* __restrict__ ncnt,
                       const float* g0, const float* b0, const float* m0, const float* v0,
                       const float* g1, const float* b1, const float* m1, const float* v1,
                       const float* g2, const float* b2, const float* m2, const float* v2,
                       float* __restrict__ sh, float* __restrict__ coords_out,
                       const float* __restrict__ pw, const float* __restrict__ gi,
                       const float* __restrict__ ff1, const float* __restrict__ ff2,
                       ushort_t* __restrict__ tpw, ushort_t* __restrict__ tgi,
                       ushort_t* __restrict__ tff1, ushort_t* __restrict__ tff2) {
    int bid = blockIdx.x;
    if (bid < B_) {
        int b = bid, n = threadIdx.x;
        __shared__ float se[N_], sp[N_];
        __shared__ int sge[N_], sgp[N_];
        float eta = coords[(b * N_ + n) * 2 + 0];
        float phi = coords[(b * N_ + n) * 2 + 1];
        coords_out[b * 512 + n] = coords[b * 512 + n];
        coords_out[b * 512 + 256 + n] = coords[b * 512 + 256 + n];
        se[n] = eta; sp[n] = phi;
        __syncthreads();
        for (int s = 128; s > 0; s >>= 1) {
            if (n < s) {
                se[n] = fminf(se[n], se[n + s]);
                sp[n] = fminf(sp[n], sp[n + s]);
            }
            __syncthreads();
        }
        float emin = se[0], pmin = sp[0];
        int gi2 = (int)((eta - emin) / 0.1f); gi2 = gi2 < 0 ? 0 : (gi2 > 127 ? 127 : gi2);
        int pi = (int)((phi - pmin) / 0.1f); pi = pi < 0 ? 0 : (pi > 127 ? 127 : pi);
        sge[n] = gi2; sgp[n] = pi;
        __syncthreads();
        int cnt = 0;
        ushort_t* out = nbr + ((size_t)b * N_ + n) * N_;
        for (int m = 0; m < N_; ++m) {
            int dh = sge[m] - gi2 + 3;
            int dv = sgp[m] - pi + 3;
            if (((unsigned)dh < 8u) && ((unsigned)dv < 8u))
                out[cnt++] = (ushort_t)(m | ((dh * 8 + dv) << 8));
        }
        ncnt[b * N_ + n] = cnt;
    } else if (bid == B_) {
        int c = threadIdx.x;
        float s;
        s = g0[c] * rsqrtf(v0[c] + 1e-3f); sh[c]        = s; sh[256 + c]  = b0[c] - m0[c] * s;
        s = g1[c] * rsqrtf(v1[c] + 1e-3f); sh[512 + c]  = s; sh[768 + c]  = b1[c] - m1[c] * s;
        s = g2[c] * rsqrtf(v2[c] + 1e-3f); sh[1024 + c] = s; sh[1280 + c] = b2[c] - m2[c] * s;
    } else {
        __shared__ float s[32][33];
        int t2 = bid - (B_ + 1);
        const float* W; ushort_t* T; int K, Nn, t;
        if (t2 < 64)       { W = pw;  T = tpw;  K = 256;  Nn = 256;  t = t2; }
        else if (t2 < 128) { W = gi;  T = tgi;  K = 256;  Nn = 256;  t = t2 - 64; }
        else if (t2 < 384) { W = ff1; T = tff1; K = 256;  Nn = 1024; t = t2 - 128; }
        else               { W = ff2; T = tff2; K = 1024; Nn = 256;  t = t2 - 384; }
        int ntiles_n = Nn >> 5;
        int n0 = (t % ntiles_n) << 5, k0 = (t / ntiles_n) << 5;
        int tx = threadIdx.x & 31, ty = threadIdx.x >> 5;
        #pragma unroll
        for (int j = 0; j < 4; ++j)
            s[ty + j * 8][tx] = W[(size_t)(k0 + ty + j * 8) * Nn + n0 + tx];
        __syncthreads();
        #pragma unroll
        for (int j = 0; j < 4; ++j)
            T[(size_t)(n0 + ty + j * 8) * K + k0 + tx] = f2bf(s[tx][ty + j * 8]);
    }
}

// ==== CPE: one wave per point, float4 channels, 4-way unrolled neighbors ====
__global__ __launch_bounds__(256) void k_cpe2(
        const float* __restrict__ x,
        const ushort_t* __restrict__ nbr, const int* __restrict__ ncnt,
        const float* __restrict__ dwk, const float* __restrict__ dwb,
        ushort_t* __restrict__ t0) {
    int wv = threadIdx.x >> 6, lane = threadIdx.x & 63;
    int bn = blockIdx.x * 4 + wv;
    int b = bn >> 8;
    int c0 = lane * 4;
    int cnt = ncnt[bn];
    const ushort_t* lst = nbr + (size_t)bn * N_;
    const float* xb = x + (size_t)b * N_ * C_;
    float4 a0 = *(const float4*)(dwb + c0);
    float4 a1 = {0.f, 0.f, 0.f, 0.f};
    float4 a2 = {0.f, 0.f, 0.f, 0.f};
    float4 a3 = {0.f, 0.f, 0.f, 0.f};
    int i = 0;
    for (; i + 4 <= cnt; i += 4) {
        int pk0 = lst[i], pk1 = lst[i + 1], pk2 = lst[i + 2], pk3 = lst[i + 3];
        float4 w0 = *(const float4*)(dwk + (pk0 >> 8) * C_ + c0);
        float4 v0 = *(const float4*)(xb + (pk0 & 255) * C_ + c0);
        float4 w1 = *(const float4*)(dwk + (pk1 >> 8) * C_ + c0);
        float4 v1 = *(const float4*)(xb + (pk1 & 255) * C_ + c0);
        float4 w2 = *(const float4*)(dwk + (pk2 >> 8) * C_ + c0);
        float4 v2 = *(const float4*)(xb + (pk2 & 255) * C_ + c0);
        float4 w3 = *(const float4*)(dwk + (pk3 >> 8) * C_ + c0);
        float4 v3 = *(const float4*)(xb + (pk3 & 255) * C_ + c0);
        a0.x = fmaf(w0.x, v0.x, a0.x); a0.y = fmaf(w0.y, v0.y, a0.y);
        a0.z = fmaf(w0.z, v0.z, a0.z); a0.w = fmaf(w0.w, v0.w, a0.w);
        a1.x = fmaf(w1.x, v1.x, a1.x); a1.y = fmaf(w1.y, v1.y, a1.y);
        a1.z = fmaf(w1.z, v1.z, a1.z); a1.w = fmaf(w1.w, v1.w, a1.w);
        a2.x = fmaf(w2.x, v2.x, a2.x); a2.y = fmaf(w2.y, v2.y, a2.y);
        a2.z = fmaf(w2.z, v2.z, a2.z); a2.w = fmaf(w2.w, v2.w, a2.w);
        a3.x = fmaf(w3.x, v3.x, a3.x); a3.y = fmaf(w3.y, v3.y, a3.y);
        a3.z = fmaf(w3.z, v3.z, a3.z); a3.w = fmaf(w3.w, v3.w, a3.w);
    }
    for (; i < cnt; ++i) {
        int pk = lst[i];
        float4 w = *(const float4*)(dwk + (pk >> 8) * C_ + c0);
        float4 v = *(const float4*)(xb + (pk & 255) * C_ + c0);
        a0.x = fmaf(w.x, v.x, a0.x); a0.y = fmaf(w.y, v.y, a0.y);
        a0.z = fmaf(w.z, v.z, a0.z); a0.w = fmaf(w.w, v.w, a0.w);
    }
    a0.x += a1.x + a2.x + a3.x;
    a0.y += a1.y + a2.y + a3.y;
    a0.z += a1.z + a2.z + a3.z;
    a0.w += a1.w + a2.w + a3.w;
    ushort4 ob; ob.x = f2bf(a0.x); ob.y = f2bf(a0.y); ob.z = f2bf(a0.z); ob.w = f2bf(a0.w);
    *(ushort4*)(t0 + (size_t)bn * C_ + c0) = ob;
}

// ---- row GEMM, 8 waves: BM=32, BN=256; A resident LDS (16KB), B in REGISTERS ----
// wave wv owns cols [wv*32,+32); B panel K=256 preloaded: 16 x bf16x8 (64 VGPR)
// No in-loop barriers: single syncthreads after staging, then 64 MFMAs.
template <int EPI>
__global__ __launch_bounds__(512) void k_gemmrow8(
    const ushort_t* __restrict__ A, const ushort_t* __restrict__ Wt,
    const float* __restrict__ bias,
    ushort_t* __restrict__ Cb,
    const float* __restrict__ residf, const ushort_t* __restrict__ residb,
    const float* __restrict__ p0, const float* __restrict__ p1,
    const float* __restrict__ p2, const float* __restrict__ p3,
    float* __restrict__ partial, const float* __restrict__ w1,
    const float* __restrict__ b1) {
    const int K = 256;
    __shared__ __align__(16) ushort_t sA[8192];       // 32x256 = 16KB, 4 k-chunks
    __shared__ float red[8][32][2];
    __shared__ float sg[C_];
    __shared__ float sgp[2][C_];
    __shared__ float sgv[C_];
    int tid = threadIdx.x, lane = tid & 63, wv = tid >> 6;
    int rowBase = blockIdx.x * 32;
    int l16 = lane & 15, g = (lane >> 4) & 3;

    // A: full 16KB via 2 GLL/thread
    const ushort_t* aSrc[2];
    unsigned aOff[2];
    #pragma unroll
    for (int q = 0; q < 2; ++q) {
        unsigned P = q * 8192u + (unsigned)tid * 16u;
        unsigned L = swz64(P);
        unsigned chunk = L >> 12;
        unsigned row = (L >> 7) & 31u;
        unsigned k = (L & 127u) >> 1;
        aSrc[q] = A + (size_t)(rowBase + row) * K + chunk * 64 + k;
        aOff[q] = q * 8192u + (unsigned)wv * 1024u;
    }
    #pragma unroll
    for (int q = 0; q < 2; ++q) GLL(aSrc[q], (char*)sA + aOff[q]);

    // B: register preload — 16 bf16x8 per thread (wave covers its 32 cols x K=256)
    bf16x8 bfr[4][2][2];
    const ushort_t* bbase = Wt + (size_t)(wv * 32 + l16) * K + g * 8;
    #pragma unroll
    for (int t = 0; t < 4; ++t)
        #pragma unroll
        for (int kk = 0; kk < 2; ++kk)
            #pragma unroll
            for (int ni = 0; ni < 2; ++ni)
                bfr[t][kk][ni] = *(const bf16x8*)(bbase + (size_t)ni * 16 * K + t * 64 + kk * 32);

    if constexpr (EPI == 2) {
        // gvec prologue (overlaps in-flight loads): sg = gctx, sgv = gctx@w1 + b1
        int j = tid & 255, h = tid >> 8;
        if (h == 0) {
            int pb = (blockIdx.x >> 3) << 3;
            float s = 0.f;
            #pragma unroll
            for (int k2 = 0; k2 < 8; ++k2) s += partial[(size_t)(pb + k2) * C_ + j];
            sg[j] = s * (1.f / 256.f);
        }
        __syncthreads();
        float a2 = 0.f;
        #pragma unroll 8
        for (int c2 = h * 128; c2 < h * 128 + 128; ++c2)
            a2 = fmaf(sg[c2], w1[c2 * C_ + j], a2);
        sgp[h][j] = a2;
        __syncthreads();
        if (h == 0) sgv[j] = b1[j] + sgp[0][j] + sgp[1][j];
    }
    __syncthreads();   // drains A GLLs (+ B loads via implicit vmcnt 0)

    unsigned oA[2][2];
    #pragma unroll
    for (int mi = 0; mi < 2; ++mi)
        #pragma unroll
        for (int kk = 0; kk < 2; ++kk)
            oA[mi][kk] = swz64((unsigned)(((mi * 16 + l16) << 7) + (kk << 6) + (g << 4)));

    f32x4 acc[2][2] = {};
    #pragma unroll
    for (int t = 0; t < 4; ++t) {
        const char* cA = (const char*)sA + t * 4096;
        #pragma unroll
        for (int kk = 0; kk < 2; ++kk) {
            bf16x8 a0v = *(const bf16x8*)(cA + oA[0][kk]);
            bf16x8 a1v = *(const bf16x8*)(cA + oA[1][kk]);
            acc[0][0] = __builtin_amdgcn_mfma_f32_16x16x32_bf16(a0v, bfr[t][kk][0], acc[0][0], 0, 0, 0);
            acc[0][1] = __builtin_amdgcn_mfma_f32_16x16x32_bf16(a0v, bfr[t][kk][1], acc[0][1], 0, 0, 0);
            acc[1][0] = __builtin_amdgcn_mfma_f32_16x16x32_bf16(a1v, bfr[t][kk][0], acc[1][0], 0, 0, 0);
            acc[1][1] = __builtin_amdgcn_mfma_f32_16x16x32_bf16(a1v, bfr[t][kk][1], acc[1][1], 0, 0, 0);
        }
    }

    float bv[2];
    #pragma unroll
    for (int ni = 0; ni < 2; ++ni) bv[ni] = bias[wv * 32 + ni * 16 + l16];
    #pragma unroll
    for (int mi = 0; mi < 2; ++mi)
        #pragma unroll
        for (int ni = 0; ni < 2; ++ni)
            #pragma unroll
            for (int j = 0; j < 4; ++j)
                acc[mi][ni][j] += bv[ni];

    if constexpr (EPI == 4) {
        #pragma unroll
        for (int mi = 0; mi < 2; ++mi)
            #pragma unroll
            for (int j = 0; j < 4; ++j) {
                float s = acc[mi][0][j] + acc[mi][1][j];
                float q = acc[mi][0][j] * acc[mi][0][j] + acc[mi][1][j] * acc[mi][1][j];
                #pragma unroll
                for (int off = 1; off < 16; off <<= 1) {
                    s += __shfl_xor(s, off);
                    q += __shfl_xor(q, off);
                }
                if (l16 == 0) {
                    int r = mi * 16 + g * 4 + j;
                    red[wv][r][0] = s;
                    red[wv][r][1] = q;
                }
            }
        __syncthreads();
        float colsum[2] = {0.f, 0.f};
        #pragma unroll
        for (int mi = 0; mi < 2; ++mi)
            #pragma unroll
            for (int j = 0; j < 4; ++j) {
                int r = mi * 16 + g * 4 + j;
                float sum = 0.f, sq = 0.f;
                #pragma unroll
                for (int w = 0; w < 8; ++w) { sum += red[w][r][0]; sq += red[w][r][1]; }
                float mu = sum * (1.f / 256.f);
                float var = fmaxf(sq * (1.f / 256.f) - mu * mu, 0.f);
                float rs = rsqrtf(var + 1e-6f);
                int row = rowBase + r;
                #pragma unroll
                for (int ni = 0; ni < 2; ++ni) {
                    int col = wv * 32 + ni * 16 + l16;
                    size_t idx = (size_t)row * C_ + col;
                    float o = residf[idx] + (acc[mi][ni][j] - mu) * rs * p0[col] + p1[col];
                    Cb[idx] = f2bf(o);
                    colsum[ni] += o;
                }
            }
        #pragma unroll
        for (int ni = 0; ni < 2; ++ni) {
            float s = colsum[ni];
            s += __shfl_xor(s, 16);
            s += __shfl_xor(s, 32);
            if (g == 0) partial[(size_t)blockIdx.x * C_ + wv * 32 + ni * 16 + l16] = s;
        }
    } else {  // EPI == 2
        #pragma unroll
        for (int ni = 0; ni < 2; ++ni) {
            int col = wv * 32 + ni * 16 + l16;
            float gv = sgv[col];
            float s0v = p0[col], h0v = p1[col], s1v = p2[col], h1v = p3[col];
            #pragma unroll
            for (int mi = 0; mi < 2; ++mi)
                #pragma unroll
                for (int j = 0; j < 4; ++j) {
                    int row = rowBase + mi * 16 + g * 4 + j;
                    size_t idx = (size_t)row * C_ + col;
                    float v = acc[mi][ni][j] + gv;
                    v = v * s0v + h0v;
                    float o = (bf2f(residb[idx]) + v) * s1v + h1v;
                    Cb[idx] = f2bf(o);
                }
        }
    }
}

// ------ FF GEMM: 512 thr / 8 waves (4x2), BM=128, BN(128|64), BK=64, dbuf -----
// grid = (rowChunks, colChunks): all col-chunks of a row-panel -> same XCD (r%8)
template <int EPI, int BN>
__global__ __launch_bounds__(512) void k_gemm128(
    const ushort_t* __restrict__ A, const ushort_t* __restrict__ Wt,
    const float* __restrict__ bias, int K, int Nn,
    ushort_t* __restrict__ Cb, float* __restrict__ Cf,
    const ushort_t* __restrict__ residb,
    const float* __restrict__ p0, const float* __restrict__ p1) {
    const int NI = BN / 32;
    const int QB = (BN == 128) ? 2 : 1;
    __shared__ __align__(16) ushort_t sA[2][8192];
    __shared__ __align__(16) ushort_t sB[2][BN * 64];
    int tid = threadIdx.x;
    int lane = tid & 63, wv = tid >> 6;
    int rowBase = blockIdx.x * 128, colBase = blockIdx.y * BN;
    int l16 = lane & 15, g = (lane >> 4) & 3;
    int wr = (wv >> 1) * 32, wc = (wv & 1) * (BN / 2);

    const ushort_t* aSrc[2];
    unsigned aOff[2];
    #pragma unroll
    for (int q = 0; q < 2; ++q) {
        unsigned P = q * 8192u + (unsigned)tid * 16u;
        unsigned L = swz64(P);
        aSrc[q] = A + (size_t)(rowBase + (L >> 7)) * K + ((L & 127u) >> 1);
        aOff[q] = q * 8192u + (unsigned)wv * 1024u;
    }
    const ushort_t* bSrc[QB];
    unsigned bOff[QB];
    #pragma unroll
    for (int q = 0; q < QB; ++q) {
        unsigned P = q * 8192u + (unsigned)tid * 16u;
        unsigned L = swz64(P);
        bSrc[q] = Wt + (size_t)(colBase + (L >> 7)) * K + ((L & 127u) >> 1);
        bOff[q] = q * 8192u + (unsigned)wv * 1024u;
    }

    unsigned oA[2][2], oB[NI][2];
    #pragma unroll
    for (int mi = 0; mi < 2; ++mi)
        #pragma unroll
        for (int kk = 0; kk < 2; ++kk)
            oA[mi][kk] = swz64((unsigned)(((wr + mi * 16 + l16) << 7) + (kk << 6) + (g << 4)));
    #pragma unroll
    for (int ni = 0; ni < NI; ++ni)
        #pragma unroll
        for (int kk = 0; kk < 2; ++kk)
            oB[ni][kk] = swz64((unsigned)(((wc + ni * 16 + l16) << 7) + (kk << 6) + (g << 4)));

    f32x4 acc[2][NI] = {};
    int nt = K >> 6;

    #pragma unroll
    for (int q = 0; q < 2; ++q) GLL(aSrc[q], (char*)sA[0] + aOff[q]);
    #pragma unroll
    for (int q = 0; q < QB; ++q) GLL(bSrc[q], (char*)sB[0] + bOff[q]);

    int cur = 0;
    for (int t = 0; t < nt; ++t) {
        if (t + 1 < nt) {
            int o = (t + 1) << 6;
            #pragma unroll
            for (int q = 0; q < 2; ++q) GLL(aSrc[q] + o, (char*)sA[cur ^ 1] + aOff[q]);
            #pragma unroll
            for (int q = 0; q < QB; ++q) GLL(bSrc[q] + o, (char*)sB[cur ^ 1] + bOff[q]);
            if constexpr (BN == 128) asm volatile("s_waitcnt vmcnt(4)" ::: "memory");
            else                     asm volatile("s_waitcnt vmcnt(3)" ::: "memory");
        } else {
            asm volatile("s_waitcnt vmcnt(0)" ::: "memory");
        }
        asm volatile("s_barrier" ::: "memory");
        const char* cA = (const char*)sA[cur];
        const char* cB = (const char*)sB[cur];
        #pragma unroll
        for (int kk = 0; kk < 2; ++kk) {
            bf16x8 af[2], bff[NI];
            #pragma unroll
            for (int mi = 0; mi < 2; ++mi) af[mi] = *(const bf16x8*)(cA + oA[mi][kk]);
            #pragma unroll
            for (int ni = 0; ni < NI; ++ni) bff[ni] = *(const bf16x8*)(cB + oB[ni][kk]);
            #pragma unroll
            for (int mi = 0; mi < 2; ++mi)
                #pragma unroll
                for (int ni = 0; ni < NI; ++ni)
                    acc[mi][ni] = __builtin_amdgcn_mfma_f32_16x16x32_bf16(af[mi], bff[ni], acc[mi][ni], 0, 0, 0);
        }
        asm volatile("s_barrier" ::: "memory");
        cur ^= 1;
    }

    #pragma unroll
    for (int ni = 0; ni < NI; ++ni) {
        int col = colBase + wc + ni * 16 + l16;
        float bvv = bias[col];
        float s0v = 0.f, h0v = 0.f;
        if constexpr (EPI == 3) { s0v = p0[col]; h0v = p1[col]; }
        #pragma unroll
        for (int mi = 0; mi < 2; ++mi)
            #pragma unroll
            for (int j = 0; j < 4; ++j) {
                int row = rowBase + wr + mi * 16 + g * 4 + j;
                size_t idx = (size_t)row * Nn + col;
                float v = acc[mi][ni][j] + bvv;
                if constexpr (EPI == 1) {
                    Cb[idx] = f2bf(fmaxf(v, 0.f));
                } else {
                    Cf[idx] = (bf2f(residb[idx]) + v) * s0v + h0v;
                }
            }
    }
}

extern "C" void kernel_launch(void* const* d_in, const int* in_sizes, int n_in,
                              void* d_out, int out_size, void* d_ws, size_t ws_size,
                              hipStream_t stream) {
    const float* x      = (const float*)d_in[0];
    const float* coords = (const float*)d_in[1];
    const float* dwk    = (const float*)d_in[2];
    const float* dwb    = (const float*)d_in[3];
    const float* pw_w   = (const float*)d_in[4];
    const float* pw_b   = (const float*)d_in[5];
    const float* ln_g   = (const float*)d_in[6];
    const float* ln_b   = (const float*)d_in[7];
    const float* gi_w1  = (const float*)d_in[8];
    const float* gi_b1  = (const float*)d_in[9];
    const float* gi_w2  = (const float*)d_in[10];
    const float* gi_b2  = (const float*)d_in[11];
    const float* bn0g = (const float*)d_in[12], *bn0b = (const float*)d_in[13];
    const float* bn0m = (const float*)d_in[14], *bn0v = (const float*)d_in[15];
    const float* bn1g = (const float*)d_in[16], *bn1b = (const float*)d_in[17];
    const float* bn1m = (const float*)d_in[18], *bn1v = (const float*)d_in[19];
    const float* bn2g = (const float*)d_in[20], *bn2b = (const float*)d_in[21];
    const float* bn2m = (const float*)d_in[22], *bn2v = (const float*)d_in[23];
    const float* w_ff1 = (const float*)d_in[24];
    const float* b_ff1 = (const float*)d_in[25];
    const float* w_ff2 = (const float*)d_in[26];
    const float* b_ff2 = (const float*)d_in[27];

    char* ws = (char*)d_ws;
    int*      ncnt    = (int*)(ws + 0);             // 32 KB
    float*    bnsh    = (float*)(ws + 32768);       // 6 KB
    float*    partial = (float*)(ws + 40960);       // 256 KB
    ushort_t* WtPW    = (ushort_t*)(ws + 303104);   // 128 KB
    ushort_t* WtGI    = (ushort_t*)(ws + 434176);   // 128 KB
    ushort_t* WtF1    = (ushort_t*)(ws + 565248);   // 512 KB
    ushort_t* WtF2    = (ushort_t*)(ws + 1089536);  // 512 KB
    ushort_t* nbr     = (ushort_t*)(ws + 1613824);  // 4 MB
    ushort_t* x1b     = (ushort_t*)(ws + 5808128);  // 4 MB
    ushort_t* x2b     = (ushort_t*)(ws + 10002432); // 4 MB
    ushort_t* t0      = (ushort_t*)(ws + 14196736); // 4 MB
    ushort_t* u_b     = (ushort_t*)(ws + 18391040); // 16 MB
    float*    outx    = (float*)d_out;

    const int M = B_ * N_;  // 8192

    // 1) geo + bnprep + wprep + coords passthrough
    k_prep<<<B_ + 1 + 640, 256, 0, stream>>>(
        coords, nbr, ncnt,
        bn0g, bn0b, bn0m, bn0v, bn1g, bn1b, bn1m, bn1v, bn2g, bn2b, bn2m, bn2v,
        bnsh, outx + (size_t)M * C_,
        pw_w, gi_w2, w_ff1, w_ff2, WtPW, WtGI, WtF1, WtF2);

    // 2) t0 = cpe(x) — wave per point
    k_cpe2<<<M / 4, 256, 0, stream>>>(x, nbr, ncnt, dwk, dwb, t0);

    // 3) x1 = x + LN(t0@pw_w + pw_b) -> x1b; colsum partials (B-in-registers)
    k_gemmrow8<4><<<M / 32, 512, 0, stream>>>(
        t0, WtPW, pw_b, x1b, x, nullptr,
        ln_g, ln_b, nullptr, nullptr,
        partial, nullptr, nullptr);

    // 4) x2 = bn1(x1 + bn0(x1@gi_w2 + gi_b2 + gvec)) -> x2b (B-in-registers)
    k_gemmrow8<2><<<M / 32, 512, 0, stream>>>(
        x1b, WtGI, gi_b2, x2b, nullptr, x1b,
        bnsh, bnsh + 256, bnsh + 512, bnsh + 768,
        partial, gi_w1, gi_b1);

    // 5) u = relu(x2 @ w_ff1 + b_ff1)   (512 thr, 8 waves)
    k_gemm128<1, 128><<<dim3(M / 128, DFF_ / 128), 512, 0, stream>>>(
        x2b, WtF1, b_ff1, C_, DFF_, u_b, nullptr, nullptr, nullptr, nullptr);

    // 6) out = bn2(x2 + u @ w_ff2 + b_ff2)   (512 thr, 8 waves)
    k_gemm128<3, 64><<<dim3(M / 128, C_ / 64), 512, 0, stream>>>(
        u_b, WtF2, b_ff2, DFF_, C_, nullptr, outx, x2b,
        bnsh + 1024, bnsh + 1280);
}

// Round 17
// 89.227 us; speedup vs baseline: 1.0348x; 1.0348x over previous
//
#include <hip/hip_runtime.h>
#include <cstdint>
#include <cstddef>

#define B_   32
#define N_   256
#define C_   256
#define DFF_ 1024

typedef unsigned short ushort_t;
typedef __attribute__((ext_vector_type(8))) short bf16x8;
typedef __attribute__((ext_vector_type(4))) float f32x4;

__device__ __forceinline__ ushort_t f2bf(float f) {
    unsigned u = __builtin_bit_cast(unsigned, f);
    u += 0x7FFFu + ((u >> 16) & 1u);
    return (ushort_t)(u >> 16);
}
__device__ __forceinline__ float bf2f(ushort_t b) {
    return __builtin_bit_cast(float, (unsigned)b << 16);
}

// 128B-row swizzle: XOR byte-bits 4-6 with row bits 7-9 -> involution
__device__ __forceinline__ unsigned swz64(unsigned a) {
    return a ^ (((a >> 7) & 7u) << 4);
}

#define GLL(src, dst) __builtin_amdgcn_global_load_lds( \
    (const __attribute__((address_space(1))) void*)(src), \
    (__attribute__((address_space(3))) void*)(dst), 16, 0, 0)

// ======== geo: blocks 0-31 grid cells + neighbor lists; block 32 bnprep ========
__global__ void k_geo(const float* __restrict__ coords,
                      ushort_t* __restrict__ nbr, int* __restrict__ ncnt,
                      const float* g0, const float* b0, const float* m0, const float* v0,
                      const float* g1, const float* b1, const float* m1, const float* v1,
                      const float* g2, const float* b2, const float* m2, const float* v2,
                      float* __restrict__ sh, float* __restrict__ coords_out) {
    int bid = blockIdx.x;
    if (bid == B_) {
        int c = threadIdx.x;
        float s;
        s = g0[c] * rsqrtf(v0[c] + 1e-3f); sh[c]        = s; sh[256 + c]  = b0[c] - m0[c] * s;
        s = g1[c] * rsqrtf(v1[c] + 1e-3f); sh[512 + c]  = s; sh[768 + c]  = b1[c] - m1[c] * s;
        s = g2[c] * rsqrtf(v2[c] + 1e-3f); sh[1024 + c] = s; sh[1280 + c] = b2[c] - m2[c] * s;
        return;
    }
    int b = bid, n = threadIdx.x;
    __shared__ float se[N_], sp[N_];
    __shared__ int sge[N_], sgp[N_];
    float eta = coords[(b * N_ + n) * 2 + 0];
    float phi = coords[(b * N_ + n) * 2 + 1];
    coords_out[b * 512 + n] = coords[b * 512 + n];
    coords_out[b * 512 + 256 + n] = coords[b * 512 + 256 + n];
    se[n] = eta; sp[n] = phi;
    __syncthreads();
    for (int s = 128; s > 0; s >>= 1) {
        if (n < s) {
            se[n] = fminf(se[n], se[n + s]);
            sp[n] = fminf(sp[n], sp[n + s]);
        }
        __syncthreads();
    }
    float emin = se[0], pmin = sp[0];
    int gi2 = (int)((eta - emin) / 0.1f); gi2 = gi2 < 0 ? 0 : (gi2 > 127 ? 127 : gi2);
    int pi = (int)((phi - pmin) / 0.1f); pi = pi < 0 ? 0 : (pi > 127 ? 127 : pi);
    sge[n] = gi2; sgp[n] = pi;
    __syncthreads();
    int cnt = 0;
    ushort_t* out = nbr + ((size_t)b * N_ + n) * N_;
    for (int m = 0; m < N_; ++m) {
        int dh = sge[m] - gi2 + 3;
        int dv = sgp[m] - pi + 3;
        if (((unsigned)dh < 8u) && ((unsigned)dv < 8u))
            out[cnt++] = (ushort_t)(m | ((dh * 8 + dv) << 8));
    }
    ncnt[b * N_ + n] = cnt;
}

// ==== cpw: blocks 0-2047 CPE (wave/point); blocks 2048-2687 weight transpose ====
__global__ __launch_bounds__(256) void k_cpw(
        const float* __restrict__ x,
        const ushort_t* __restrict__ nbr, const int* __restrict__ ncnt,
        const float* __restrict__ dwk, const float* __restrict__ dwb,
        ushort_t* __restrict__ t0,
        const float* __restrict__ pw, const float* __restrict__ gi,
        const float* __restrict__ ff1, const float* __restrict__ ff2,
        ushort_t* __restrict__ tpw, ushort_t* __restrict__ tgi,
        ushort_t* __restrict__ tff1, ushort_t* __restrict__ tff2) {
    if (blockIdx.x >= 2048) {
        // ---- weight transpose [K][N] fp32 -> [N][K] bf16 ----
        __shared__ float s[32][33];
        int t2 = blockIdx.x - 2048;
        const float* W; ushort_t* T; int K, Nn, t;
        if (t2 < 64)       { W = pw;  T = tpw;  K = 256;  Nn = 256;  t = t2; }
        else if (t2 < 128) { W = gi;  T = tgi;  K = 256;  Nn = 256;  t = t2 - 64; }
        else if (t2 < 384) { W = ff1; T = tff1; K = 256;  Nn = 1024; t = t2 - 128; }
        else               { W = ff2; T = tff2; K = 1024; Nn = 256;  t = t2 - 384; }
        int ntiles_n = Nn >> 5;
        int n0 = (t % ntiles_n) << 5, k0 = (t / ntiles_n) << 5;
        int tx = threadIdx.x & 31, ty = threadIdx.x >> 5;
        #pragma unroll
        for (int j = 0; j < 4; ++j)
            s[ty + j * 8][tx] = W[(size_t)(k0 + ty + j * 8) * Nn + n0 + tx];
        __syncthreads();
        #pragma unroll
        for (int j = 0; j < 4; ++j)
            T[(size_t)(n0 + ty + j * 8) * K + k0 + tx] = f2bf(s[tx][ty + j * 8]);
        return;
    }
    // ---- CPE ----
    int wv = threadIdx.x >> 6, lane = threadIdx.x & 63;
    int bn = blockIdx.x * 4 + wv;
    int b = bn >> 8;
    int c0 = lane * 4;
    int cnt = ncnt[bn];
    const ushort_t* lst = nbr + (size_t)bn * N_;
    const float* xb = x + (size_t)b * N_ * C_;
    float4 a0 = *(const float4*)(dwb + c0);
    float4 a1 = {0.f, 0.f, 0.f, 0.f};
    float4 a2 = {0.f, 0.f, 0.f, 0.f};
    float4 a3 = {0.f, 0.f, 0.f, 0.f};
    int i = 0;
    for (; i + 4 <= cnt; i += 4) {
        int pk0 = lst[i], pk1 = lst[i + 1], pk2 = lst[i + 2], pk3 = lst[i + 3];
        float4 w0 = *(const float4*)(dwk + (pk0 >> 8) * C_ + c0);
        float4 v0 = *(const float4*)(xb + (pk0 & 255) * C_ + c0);
        float4 w1 = *(const float4*)(dwk + (pk1 >> 8) * C_ + c0);
        float4 v1 = *(const float4*)(xb + (pk1 & 255) * C_ + c0);
        float4 w2 = *(const float4*)(dwk + (pk2 >> 8) * C_ + c0);
        float4 v2 = *(const float4*)(xb + (pk2 & 255) * C_ + c0);
        float4 w3 = *(const float4*)(dwk + (pk3 >> 8) * C_ + c0);
        float4 v3 = *(const float4*)(xb + (pk3 & 255) * C_ + c0);
        a0.x = fmaf(w0.x, v0.x, a0.x); a0.y = fmaf(w0.y, v0.y, a0.y);
        a0.z = fmaf(w0.z, v0.z, a0.z); a0.w = fmaf(w0.w, v0.w, a0.w);
        a1.x = fmaf(w1.x, v1.x, a1.x); a1.y = fmaf(w1.y, v1.y, a1.y);
        a1.z = fmaf(w1.z, v1.z, a1.z); a1.w = fmaf(w1.w, v1.w, a1.w);
        a2.x = fmaf(w2.x, v2.x, a2.x); a2.y = fmaf(w2.y, v2.y, a2.y);
        a2.z = fmaf(w2.z, v2.z, a2.z); a2.w = fmaf(w2.w, v2.w, a2.w);
        a3.x = fmaf(w3.x, v3.x, a3.x); a3.y = fmaf(w3.y, v3.y, a3.y);
        a3.z = fmaf(w3.z, v3.z, a3.z); a3.w = fmaf(w3.w, v3.w, a3.w);
    }
    for (; i < cnt; ++i) {
        int pk = lst[i];
        float4 w = *(const float4*)(dwk + (pk >> 8) * C_ + c0);
        float4 v = *(const float4*)(xb + (pk & 255) * C_ + c0);
        a0.x = fmaf(w.x, v.x, a0.x); a0.y = fmaf(w.y, v.y, a0.y);
        a0.z = fmaf(w.z, v.z, a0.z); a0.w = fmaf(w.w, v.w, a0.w);
    }
    a0.x += a1.x + a2.x + a3.x;
    a0.y += a1.y + a2.y + a3.y;
    a0.z += a1.z + a2.z + a3.z;
    a0.w += a1.w + a2.w + a3.w;
    ushort4 ob; ob.x = f2bf(a0.x); ob.y = f2bf(a0.y); ob.z = f2bf(a0.z); ob.w = f2bf(a0.w);
    *(ushort4*)(t0 + (size_t)bn * C_ + c0) = ob;
}

// ---- row GEMM, 8 waves: BM=32, BN=256, BK=64; A resident (16KB), B dbuf ----
template <int EPI>
__global__ __launch_bounds__(512) void k_gemmrow8(
    const ushort_t* __restrict__ A, const ushort_t* __restrict__ Wt,
    const float* __restrict__ bias,
    ushort_t* __restrict__ Cb,
    const float* __restrict__ residf, const ushort_t* __restrict__ residb,
    const float* __restrict__ p0, const float* __restrict__ p1,
    const float* __restrict__ p2, const float* __restrict__ p3,
    float* __restrict__ partial, const float* __restrict__ w1,
    const float* __restrict__ b1) {
    const int K = 256;
    __shared__ __align__(16) ushort_t sA[8192];       // 32x256 = 16KB, 4 k-chunks
    __shared__ __align__(16) ushort_t sB[2][16384];   // dbuf 256x64 = 2x32KB
    __shared__ float red[8][32][2];
    __shared__ float sg[C_];
    __shared__ float sgp[2][C_];
    __shared__ float sgv[C_];
    int tid = threadIdx.x, lane = tid & 63, wv = tid >> 6;
    int rowBase = blockIdx.x * 32;
    int l16 = lane & 15, g = (lane >> 4) & 3;

    const ushort_t* aSrc[2];
    unsigned aOff[2];
    #pragma unroll
    for (int q = 0; q < 2; ++q) {
        unsigned P = q * 8192u + (unsigned)tid * 16u;
        unsigned L = swz64(P);
        unsigned chunk = L >> 12;
        unsigned row = (L >> 7) & 31u;
        unsigned k = (L & 127u) >> 1;
        aSrc[q] = A + (size_t)(rowBase + row) * K + chunk * 64 + k;
        aOff[q] = q * 8192u + (unsigned)wv * 1024u;
    }
    const ushort_t* bSrc[4];
    unsigned bOff[4];
    #pragma unroll
    for (int q = 0; q < 4; ++q) {
        unsigned P = q * 8192u + (unsigned)tid * 16u;
        unsigned L = swz64(P);
        bSrc[q] = Wt + (size_t)(L >> 7) * K + ((L & 127u) >> 1);
        bOff[q] = q * 8192u + (unsigned)wv * 1024u;
    }
    #pragma unroll
    for (int q = 0; q < 2; ++q) GLL(aSrc[q], (char*)sA + aOff[q]);
    #pragma unroll
    for (int q = 0; q < 4; ++q) GLL(bSrc[q], (char*)sB[0] + bOff[q]);

    if constexpr (EPI == 2) {
        int j = tid & 255, h = tid >> 8;
        if (h == 0) {
            int pb = (blockIdx.x >> 3) << 3;
            float s = 0.f;
            #pragma unroll
            for (int k2 = 0; k2 < 8; ++k2) s += partial[(size_t)(pb + k2) * C_ + j];
            sg[j] = s * (1.f / 256.f);
        }
        __syncthreads();
        float a2 = 0.f;
        #pragma unroll 8
        for (int c2 = h * 128; c2 < h * 128 + 128; ++c2)
            a2 = fmaf(sg[c2], w1[c2 * C_ + j], a2);
        sgp[h][j] = a2;
        __syncthreads();
        if (h == 0) sgv[j] = b1[j] + sgp[0][j] + sgp[1][j];
        __syncthreads();
    }

    unsigned oA[2][2], oB[2][2];
    #pragma unroll
    for (int mi = 0; mi < 2; ++mi)
        #pragma unroll
        for (int kk = 0; kk < 2; ++kk)
            oA[mi][kk] = swz64((unsigned)(((mi * 16 + l16) << 7) + (kk << 6) + (g << 4)));
    #pragma unroll
    for (int ni = 0; ni < 2; ++ni)
        #pragma unroll
        for (int kk = 0; kk < 2; ++kk)
            oB[ni][kk] = swz64((unsigned)(((wv * 32 + ni * 16 + l16) << 7) + (kk << 6) + (g << 4)));

    f32x4 acc[2][2] = {};
    int cur = 0;
    for (int t = 0; t < 4; ++t) {
        if (t < 3) {
            int o = (t + 1) << 6;
            #pragma unroll
            for (int q = 0; q < 4; ++q) GLL(bSrc[q] + o, (char*)sB[cur ^ 1] + bOff[q]);
            asm volatile("s_waitcnt vmcnt(4)" ::: "memory");
        } else {
            asm volatile("s_waitcnt vmcnt(0)" ::: "memory");
        }
        asm volatile("s_barrier" ::: "memory");
        const char* cA = (const char*)sA + t * 4096;
        const char* cB = (const char*)sB[cur];
        #pragma unroll
        for (int kk = 0; kk < 2; ++kk) {
            bf16x8 a0v = *(const bf16x8*)(cA + oA[0][kk]);
            bf16x8 a1v = *(const bf16x8*)(cA + oA[1][kk]);
            bf16x8 b0v = *(const bf16x8*)(cB + oB[0][kk]);
            bf16x8 b1v = *(const bf16x8*)(cB + oB[1][kk]);
            acc[0][0] = __builtin_amdgcn_mfma_f32_16x16x32_bf16(a0v, b0v, acc[0][0], 0, 0, 0);
            acc[0][1] = __builtin_amdgcn_mfma_f32_16x16x32_bf16(a0v, b1v, acc[0][1], 0, 0, 0);
            acc[1][0] = __builtin_amdgcn_mfma_f32_16x16x32_bf16(a1v, b0v, acc[1][0], 0, 0, 0);
            acc[1][1] = __builtin_amdgcn_mfma_f32_16x16x32_bf16(a1v, b1v, acc[1][1], 0, 0, 0);
        }
        asm volatile("s_barrier" ::: "memory");
        cur ^= 1;
    }

    float bv[2];
    #pragma unroll
    for (int ni = 0; ni < 2; ++ni) bv[ni] = bias[wv * 32 + ni * 16 + l16];
    #pragma unroll
    for (int mi = 0; mi < 2; ++mi)
        #pragma unroll
        for (int ni = 0; ni < 2; ++ni)
            #pragma unroll
            for (int j = 0; j < 4; ++j)
                acc[mi][ni][j] += bv[ni];

    if constexpr (EPI == 4) {
        #pragma unroll
        for (int mi = 0; mi < 2; ++mi)
            #pragma unroll
            for (int j = 0; j < 4; ++j) {
                float s = acc[mi][0][j] + acc[mi][1][j];
                float q = acc[mi][0][j] * acc[mi][0][j] + acc[mi][1][j] * acc[mi][1][j];
                #pragma unroll
                for (int off = 1; off < 16; off <<= 1) {
                    s += __shfl_xor(s, off);
                    q += __shfl_xor(q, off);
                }
                if (l16 == 0) {
                    int r = mi * 16 + g * 4 + j;
                    red[wv][r][0] = s;
                    red[wv][r][1] = q;
                }
            }
        __syncthreads();
        float colsum[2] = {0.f, 0.f};
        #pragma unroll
        for (int mi = 0; mi < 2; ++mi)
            #pragma unroll
            for (int j = 0; j < 4; ++j) {
                int r = mi * 16 + g * 4 + j;
                float sum = 0.f, sq = 0.f;
                #pragma unroll
                for (int w = 0; w < 8; ++w) { sum += red[w][r][0]; sq += red[w][r][1]; }
                float mu = sum * (1.f / 256.f);
                float var = fmaxf(sq * (1.f / 256.f) - mu * mu, 0.f);
                float rs = rsqrtf(var + 1e-6f);
                int row = rowBase + r;
                #pragma unroll
                for (int ni = 0; ni < 2; ++ni) {
                    int col = wv * 32 + ni * 16 + l16;
                    size_t idx = (size_t)row * C_ + col;
                    float o = residf[idx] + (acc[mi][ni][j] - mu) * rs * p0[col] + p1[col];
                    Cb[idx] = f2bf(o);
                    colsum[ni] += o;
                }
            }
        #pragma unroll
        for (int ni = 0; ni < 2; ++ni) {
            float s = colsum[ni];
            s += __shfl_xor(s, 16);
            s += __shfl_xor(s, 32);
            if (g == 0) partial[(size_t)blockIdx.x * C_ + wv * 32 + ni * 16 + l16] = s;
        }
    } else {  // EPI == 2
        #pragma unroll
        for (int ni = 0; ni < 2; ++ni) {
            int col = wv * 32 + ni * 16 + l16;
            float gv = sgv[col];
            float s0v = p0[col], h0v = p1[col], s1v = p2[col], h1v = p3[col];
            #pragma unroll
            for (int mi = 0; mi < 2; ++mi)
                #pragma unroll
                for (int j = 0; j < 4; ++j) {
                    int row = rowBase + mi * 16 + g * 4 + j;
                    size_t idx = (size_t)row * C_ + col;
                    float v = acc[mi][ni][j] + gv;
                    v = v * s0v + h0v;
                    float o = (bf2f(residb[idx]) + v) * s1v + h1v;
                    Cb[idx] = f2bf(o);
                }
        }
    }
}

// ------ FF GEMM: 512 thr / 8 waves (4x2), BM=128, BN(128|64), BK=64, dbuf -----
// grid = (rowChunks, colChunks): all col-chunks of a row-panel -> same XCD (r%8)
template <int EPI, int BN>
__global__ __launch_bounds__(512) void k_gemm128(
    const ushort_t* __restrict__ A, const ushort_t* __restrict__ Wt,
    const float* __restrict__ bias, int K, int Nn,
    ushort_t* __restrict__ Cb, float* __restrict__ Cf,
    const ushort_t* __restrict__ residb,
    const float* __restrict__ p0, const float* __restrict__ p1) {
    const int NI = BN / 32;
    const int QB = (BN == 128) ? 2 : 1;
    __shared__ __align__(16) ushort_t sA[2][8192];
    __shared__ __align__(16) ushort_t sB[2][BN * 64];
    int tid = threadIdx.x;
    int lane = tid & 63, wv = tid >> 6;
    int rowBase = blockIdx.x * 128, colBase = blockIdx.y * BN;
    int l16 = lane & 15, g = (lane >> 4) & 3;
    int wr = (wv >> 1) * 32, wc = (wv & 1) * (BN / 2);

    const ushort_t* aSrc[2];
    unsigned aOff[2];
    #pragma unroll
    for (int q = 0; q < 2; ++q) {
        unsigned P = q * 8192u + (unsigned)tid * 16u;
        unsigned L = swz64(P);
        aSrc[q] = A + (size_t)(rowBase + (L >> 7)) * K + ((L & 127u) >> 1);
        aOff[q] = q * 8192u + (unsigned)wv * 1024u;
    }
    const ushort_t* bSrc[QB];
    unsigned bOff[QB];
    #pragma unroll
    for (int q = 0; q < QB; ++q) {
        unsigned P = q * 8192u + (unsigned)tid * 16u;
        unsigned L = swz64(P);
        bSrc[q] = Wt + (size_t)(colBase + (L >> 7)) * K + ((L & 127u) >> 1);
        bOff[q] = q * 8192u + (unsigned)wv * 1024u;
    }

    unsigned oA[2][2], oB[NI][2];
    #pragma unroll
    for (int mi = 0; mi < 2; ++mi)
        #pragma unroll
        for (int kk = 0; kk < 2; ++kk)
            oA[mi][kk] = swz64((unsigned)(((wr + mi * 16 + l16) << 7) + (kk << 6) + (g << 4)));
    #pragma unroll
    for (int ni = 0; ni < NI; ++ni)
        #pragma unroll
        for (int kk = 0; kk < 2; ++kk)
            oB[ni][kk] = swz64((unsigned)(((wc + ni * 16 + l16) << 7) + (kk << 6) + (g << 4)));

    f32x4 acc[2][NI] = {};
    int nt = K >> 6;

    #pragma unroll
    for (int q = 0; q < 2; ++q) GLL(aSrc[q], (char*)sA[0] + aOff[q]);
    #pragma unroll
    for (int q = 0; q < QB; ++q) GLL(bSrc[q], (char*)sB[0] + bOff[q]);

    int cur = 0;
    for (int t = 0; t < nt; ++t) {
        if (t + 1 < nt) {
            int o = (t + 1) << 6;
            #pragma unroll
            for (int q = 0; q < 2; ++q) GLL(aSrc[q] + o, (char*)sA[cur ^ 1] + aOff[q]);
            #pragma unroll
            for (int q = 0; q < QB; ++q) GLL(bSrc[q] + o, (char*)sB[cur ^ 1] + bOff[q]);
            if constexpr (BN == 128) asm volatile("s_waitcnt vmcnt(4)" ::: "memory");
            else                     asm volatile("s_waitcnt vmcnt(3)" ::: "memory");
        } else {
            asm volatile("s_waitcnt vmcnt(0)" ::: "memory");
        }
        asm volatile("s_barrier" ::: "memory");
        const char* cA = (const char*)sA[cur];
        const char* cB = (const char*)sB[cur];
        #pragma unroll
        for (int kk = 0; kk < 2; ++kk) {
            bf16x8 af[2], bff[NI];
            #pragma unroll
            for (int mi = 0; mi < 2; ++mi) af[mi] = *(const bf16x8*)(cA + oA[mi][kk]);
            #pragma unroll
            for (int ni = 0; ni < NI; ++ni) bff[ni] = *(const bf16x8*)(cB + oB[ni][kk]);
            #pragma unroll
            for (int mi = 0; mi < 2; ++mi)
                #pragma unroll
                for (int ni = 0; ni < NI; ++ni)
                    acc[mi][ni] = __builtin_amdgcn_mfma_f32_16x16x32_bf16(af[mi], bff[ni], acc[mi][ni], 0, 0, 0);
        }
        asm volatile("s_barrier" ::: "memory");
        cur ^= 1;
    }

    #pragma unroll
    for (int ni = 0; ni < NI; ++ni) {
        int col = colBase + wc + ni * 16 + l16;
        float bvv = bias[col];
        float s0v = 0.f, h0v = 0.f;
        if constexpr (EPI == 3) { s0v = p0[col]; h0v = p1[col]; }
        #pragma unroll
        for (int mi = 0; mi < 2; ++mi)
            #pragma unroll
            for (int j = 0; j < 4; ++j) {
                int row = rowBase + wr + mi * 16 + g * 4 + j;
                size_t idx = (size_t)row * Nn + col;
                float v = acc[mi][ni][j] + bvv;
                if constexpr (EPI == 1) {
                    Cb[idx] = f2bf(fmaxf(v, 0.f));
                } else {
                    Cf[idx] = (bf2f(residb[idx]) + v) * s0v + h0v;
                }
            }
    }
}

extern "C" void kernel_launch(void* const* d_in, const int* in_sizes, int n_in,
                              void* d_out, int out_size, void* d_ws, size_t ws_size,
                              hipStream_t stream) {
    const float* x      = (const float*)d_in[0];
    const float* coords = (const float*)d_in[1];
    const float* dwk    = (const float*)d_in[2];
    const float* dwb    = (const float*)d_in[3];
    const float* pw_w   = (const float*)d_in[4];
    const float* pw_b   = (const float*)d_in[5];
    const float* ln_g   = (const float*)d_in[6];
    const float* ln_b   = (const float*)d_in[7];
    const float* gi_w1  = (const float*)d_in[8];
    const float* gi_b1  = (const float*)d_in[9];
    const float* gi_w2  = (const float*)d_in[10];
    const float* gi_b2  = (const float*)d_in[11];
    const float* bn0g = (const float*)d_in[12], *bn0b = (const float*)d_in[13];
    const float* bn0m = (const float*)d_in[14], *bn0v = (const float*)d_in[15];
    const float* bn1g = (const float*)d_in[16], *bn1b = (const float*)d_in[17];
    const float* bn1m = (const float*)d_in[18], *bn1v = (const float*)d_in[19];
    const float* bn2g = (const float*)d_in[20], *bn2b = (const float*)d_in[21];
    const float* bn2m = (const float*)d_in[22], *bn2v = (const float*)d_in[23];
    const float* w_ff1 = (const float*)d_in[24];
    const float* b_ff1 = (const float*)d_in[25];
    const float* w_ff2 = (const float*)d_in[26];
    const float* b_ff2 = (const float*)d_in[27];

    char* ws = (char*)d_ws;
    int*      ncnt    = (int*)(ws + 0);             // 32 KB
    float*    bnsh    = (float*)(ws + 32768);       // 6 KB
    float*    partial = (float*)(ws + 40960);       // 256 KB
    ushort_t* WtPW    = (ushort_t*)(ws + 303104);   // 128 KB
    ushort_t* WtGI    = (ushort_t*)(ws + 434176);   // 128 KB
    ushort_t* WtF1    = (ushort_t*)(ws + 565248);   // 512 KB
    ushort_t* WtF2    = (ushort_t*)(ws + 1089536);  // 512 KB
    ushort_t* nbr     = (ushort_t*)(ws + 1613824);  // 4 MB
    ushort_t* x1b     = (ushort_t*)(ws + 5808128);  // 4 MB
    ushort_t* x2b     = (ushort_t*)(ws + 10002432); // 4 MB
    ushort_t* t0      = (ushort_t*)(ws + 14196736); // 4 MB
    ushort_t* u_b     = (ushort_t*)(ws + 18391040); // 16 MB
    float*    outx    = (float*)d_out;

    const int M = B_ * N_;  // 8192

    // 1) geo + bnprep + coords passthrough (33 blocks — short critical path)
    k_geo<<<B_ + 1, N_, 0, stream>>>(
        coords, nbr, ncnt,
        bn0g, bn0b, bn0m, bn0v, bn1g, bn1b, bn1m, bn1v, bn2g, bn2b, bn2m, bn2v,
        bnsh, outx + (size_t)M * C_);

    // 2) CPE (2048 blocks) + weight transpose (640 blocks) co-scheduled
    k_cpw<<<2048 + 640, 256, 0, stream>>>(
        x, nbr, ncnt, dwk, dwb, t0,
        pw_w, gi_w2, w_ff1, w_ff2, WtPW, WtGI, WtF1, WtF2);

    // 3) x1 = x + LN(t0@pw_w + pw_b) -> x1b; colsum partials (8-wave)
    k_gemmrow8<4><<<M / 32, 512, 0, stream>>>(
        t0, WtPW, pw_b, x1b, x, nullptr,
        ln_g, ln_b, nullptr, nullptr,
        partial, nullptr, nullptr);

    // 4) x2 = bn1(x1 + bn0(x1@gi_w2 + gi_b2 + gvec)) -> x2b (8-wave)
    k_gemmrow8<2><<<M / 32, 512, 0, stream>>>(
        x1b, WtGI, gi_b2, x2b, nullptr, x1b,
        bnsh, bnsh + 256, bnsh + 512, bnsh + 768,
        partial, gi_w1, gi_b1);

    // 5) u = relu(x2 @ w_ff1 + b_ff1)   (512 thr, 8 waves)
    k_gemm128<1, 128><<<dim3(M / 128, DFF_ / 128), 512, 0, stream>>>(
        x2b, WtF1, b_ff1, C_, DFF_, u_b, nullptr, nullptr, nullptr, nullptr);

    // 6) out = bn2(x2 + u @ w_ff2 + b_ff2)   (512 thr, 8 waves)
    k_gemm128<3, 64><<<dim3(M / 128, C_ / 64), 512, 0, stream>>>(
        u_b, WtF2, b_ff2, DFF_, C_, nullptr, outx, x2b,
        bnsh + 1024, bnsh + 1280);
}

// Round 18
// 87.951 us; speedup vs baseline: 1.0498x; 1.0145x over previous
//
#include <hip/hip_runtime.h>
#include <cstdint>
#include <cstddef>

#define B_   32
#define N_   256
#define C_   256
#define DFF_ 1024

typedef unsigned short ushort_t;
typedef __attribute__((ext_vector_type(8))) short bf16x8;
typedef __attribute__((ext_vector_type(4))) float f32x4;

__device__ __forceinline__ ushort_t f2bf(float f) {
    unsigned u = __builtin_bit_cast(unsigned, f);
    u += 0x7FFFu + ((u >> 16) & 1u);
    return (ushort_t)(u >> 16);
}
__device__ __forceinline__ float bf2f(ushort_t b) {
    return __builtin_bit_cast(float, (unsigned)b << 16);
}

// 128B-row swizzle: XOR byte-bits 4-6 with row bits 7-9 -> involution
__device__ __forceinline__ unsigned swz64(unsigned a) {
    return a ^ (((a >> 7) & 7u) << 4);
}

#define GLL(src, dst) __builtin_amdgcn_global_load_lds( \
    (const __attribute__((address_space(1))) void*)(src), \
    (__attribute__((address_space(3))) void*)(dst), 16, 0, 0)

// ======== geo: blocks 0-31 grid cells + neighbor lists; block 32 bnprep ========
__global__ void k_geo(const float* __restrict__ coords,
                      ushort_t* __restrict__ nbr, int* __restrict__ ncnt,
                      const float* g0, const float* b0, const float* m0, const float* v0,
                      const float* g1, const float* b1, const float* m1, const float* v1,
                      const float* g2, const float* b2, const float* m2, const float* v2,
                      float* __restrict__ sh, float* __restrict__ coords_out) {
    int bid = blockIdx.x;
    if (bid == B_) {
        int c = threadIdx.x;
        float s;
        s = g0[c] * rsqrtf(v0[c] + 1e-3f); sh[c]        = s; sh[256 + c]  = b0[c] - m0[c] * s;
        s = g1[c] * rsqrtf(v1[c] + 1e-3f); sh[512 + c]  = s; sh[768 + c]  = b1[c] - m1[c] * s;
        s = g2[c] * rsqrtf(v2[c] + 1e-3f); sh[1024 + c] = s; sh[1280 + c] = b2[c] - m2[c] * s;
        return;
    }
    int b = bid, n = threadIdx.x;
    __shared__ float se[N_], sp[N_];
    __shared__ int sge[N_], sgp[N_];
    float eta = coords[(b * N_ + n) * 2 + 0];
    float phi = coords[(b * N_ + n) * 2 + 1];
    coords_out[b * 512 + n] = coords[b * 512 + n];
    coords_out[b * 512 + 256 + n] = coords[b * 512 + 256 + n];
    se[n] = eta; sp[n] = phi;
    __syncthreads();
    for (int s = 128; s > 0; s >>= 1) {
        if (n < s) {
            se[n] = fminf(se[n], se[n + s]);
            sp[n] = fminf(sp[n], sp[n + s]);
        }
        __syncthreads();
    }
    float emin = se[0], pmin = sp[0];
    int gi2 = (int)((eta - emin) / 0.1f); gi2 = gi2 < 0 ? 0 : (gi2 > 127 ? 127 : gi2);
    int pi = (int)((phi - pmin) / 0.1f); pi = pi < 0 ? 0 : (pi > 127 ? 127 : pi);
    sge[n] = gi2; sgp[n] = pi;
    __syncthreads();
    int cnt = 0;
    ushort_t* out = nbr + ((size_t)b * N_ + n) * N_;
    for (int m = 0; m < N_; ++m) {
        int dh = sge[m] - gi2 + 3;
        int dv = sgp[m] - pi + 3;
        if (((unsigned)dh < 8u) && ((unsigned)dv < 8u))
            out[cnt++] = (ushort_t)(m | ((dh * 8 + dv) << 8));
    }
    ncnt[b * N_ + n] = cnt;
}

// ==== cpw: blocks 0-2047 CPE (XCD-chunked swizzle); blocks 2048+ wprep ====
__global__ __launch_bounds__(256) void k_cpw(
        const float* __restrict__ x,
        const ushort_t* __restrict__ nbr, const int* __restrict__ ncnt,
        const float* __restrict__ dwk, const float* __restrict__ dwb,
        ushort_t* __restrict__ t0,
        const float* __restrict__ pw, const float* __restrict__ gi,
        const float* __restrict__ ff1, const float* __restrict__ ff2,
        ushort_t* __restrict__ tpw, ushort_t* __restrict__ tgi,
        ushort_t* __restrict__ tff1, ushort_t* __restrict__ tff2) {
    if (blockIdx.x >= 2048) {
        // ---- weight transpose [K][N] fp32 -> [N][K] bf16 ----
        __shared__ float s[32][33];
        int t2 = blockIdx.x - 2048;
        const float* W; ushort_t* T; int K, Nn, t;
        if (t2 < 64)       { W = pw;  T = tpw;  K = 256;  Nn = 256;  t = t2; }
        else if (t2 < 128) { W = gi;  T = tgi;  K = 256;  Nn = 256;  t = t2 - 64; }
        else if (t2 < 384) { W = ff1; T = tff1; K = 256;  Nn = 1024; t = t2 - 128; }
        else               { W = ff2; T = tff2; K = 1024; Nn = 256;  t = t2 - 384; }
        int ntiles_n = Nn >> 5;
        int n0 = (t % ntiles_n) << 5, k0 = (t / ntiles_n) << 5;
        int tx = threadIdx.x & 31, ty = threadIdx.x >> 5;
        #pragma unroll
        for (int j = 0; j < 4; ++j)
            s[ty + j * 8][tx] = W[(size_t)(k0 + ty + j * 8) * Nn + n0 + tx];
        __syncthreads();
        #pragma unroll
        for (int j = 0; j < 4; ++j)
            T[(size_t)(n0 + ty + j * 8) * K + k0 + tx] = f2bf(s[tx][ty + j * 8]);
        return;
    }
    // ---- CPE; XCD-chunked block swizzle (2048 = 8 XCDs x 256 contiguous) ----
    int lb = (blockIdx.x & 7) * 256 + (blockIdx.x >> 3);
    int wv = threadIdx.x >> 6, lane = threadIdx.x & 63;
    int bn = lb * 4 + wv;
    int b = bn >> 8;
    int c0 = lane * 4;
    int cnt = ncnt[bn];
    const ushort_t* lst = nbr + (size_t)bn * N_;
    const float* xb = x + (size_t)b * N_ * C_;
    float4 a0 = *(const float4*)(dwb + c0);
    float4 a1 = {0.f, 0.f, 0.f, 0.f};
    float4 a2 = {0.f, 0.f, 0.f, 0.f};
    float4 a3 = {0.f, 0.f, 0.f, 0.f};
    int i = 0;
    for (; i + 4 <= cnt; i += 4) {
        int pk0 = lst[i], pk1 = lst[i + 1], pk2 = lst[i + 2], pk3 = lst[i + 3];
        float4 w0 = *(const float4*)(dwk + (pk0 >> 8) * C_ + c0);
        float4 v0 = *(const float4*)(xb + (pk0 & 255) * C_ + c0);
        float4 w1 = *(const float4*)(dwk + (pk1 >> 8) * C_ + c0);
        float4 v1 = *(const float4*)(xb + (pk1 & 255) * C_ + c0);
        float4 w2 = *(const float4*)(dwk + (pk2 >> 8) * C_ + c0);
        float4 v2 = *(const float4*)(xb + (pk2 & 255) * C_ + c0);
        float4 w3 = *(const float4*)(dwk + (pk3 >> 8) * C_ + c0);
        float4 v3 = *(const float4*)(xb + (pk3 & 255) * C_ + c0);
        a0.x = fmaf(w0.x, v0.x, a0.x); a0.y = fmaf(w0.y, v0.y, a0.y);
        a0.z = fmaf(w0.z, v0.z, a0.z); a0.w = fmaf(w0.w, v0.w, a0.w);
        a1.x = fmaf(w1.x, v1.x, a1.x); a1.y = fmaf(w1.y, v1.y, a1.y);
        a1.z = fmaf(w1.z, v1.z, a1.z); a1.w = fmaf(w1.w, v1.w, a1.w);
        a2.x = fmaf(w2.x, v2.x, a2.x); a2.y = fmaf(w2.y, v2.y, a2.y);
        a2.z = fmaf(w2.z, v2.z, a2.z); a2.w = fmaf(w2.w, v2.w, a2.w);
        a3.x = fmaf(w3.x, v3.x, a3.x); a3.y = fmaf(w3.y, v3.y, a3.y);
        a3.z = fmaf(w3.z, v3.z, a3.z); a3.w = fmaf(w3.w, v3.w, a3.w);
    }
    for (; i < cnt; ++i) {
        int pk = lst[i];
        float4 w = *(const float4*)(dwk + (pk >> 8) * C_ + c0);
        float4 v = *(const float4*)(xb + (pk & 255) * C_ + c0);
        a0.x = fmaf(w.x, v.x, a0.x); a0.y = fmaf(w.y, v.y, a0.y);
        a0.z = fmaf(w.z, v.z, a0.z); a0.w = fmaf(w.w, v.w, a0.w);
    }
    a0.x += a1.x + a2.x + a3.x;
    a0.y += a1.y + a2.y + a3.y;
    a0.z += a1.z + a2.z + a3.z;
    a0.w += a1.w + a2.w + a3.w;
    ushort4 ob; ob.x = f2bf(a0.x); ob.y = f2bf(a0.y); ob.z = f2bf(a0.z); ob.w = f2bf(a0.w);
    *(ushort4*)(t0 + (size_t)bn * C_ + c0) = ob;
}

// ---- row GEMM, 8 waves: BM=32, BN=256, BK=64; A resident (16KB), B dbuf ----
template <int EPI>
__global__ __launch_bounds__(512) void k_gemmrow8(
    const ushort_t* __restrict__ A, const ushort_t* __restrict__ Wt,
    const float* __restrict__ bias,
    ushort_t* __restrict__ Cb,
    const float* __restrict__ residf, const ushort_t* __restrict__ residb,
    const float* __restrict__ p0, const float* __restrict__ p1,
    const float* __restrict__ p2, const float* __restrict__ p3,
    float* __restrict__ partial, const float* __restrict__ w1,
    const float* __restrict__ b1) {
    const int K = 256;
    __shared__ __align__(16) ushort_t sA[8192];       // 32x256 = 16KB, 4 k-chunks
    __shared__ __align__(16) ushort_t sB[2][16384];   // dbuf 256x64 = 2x32KB
    __shared__ float red[8][32][2];
    __shared__ float sg[C_];
    __shared__ float sgp[2][C_];
    __shared__ float sgv[C_];
    int tid = threadIdx.x, lane = tid & 63, wv = tid >> 6;
    int rowBase = blockIdx.x * 32;
    int l16 = lane & 15, g = (lane >> 4) & 3;

    const ushort_t* aSrc[2];
    unsigned aOff[2];
    #pragma unroll
    for (int q = 0; q < 2; ++q) {
        unsigned P = q * 8192u + (unsigned)tid * 16u;
        unsigned L = swz64(P);
        unsigned chunk = L >> 12;
        unsigned row = (L >> 7) & 31u;
        unsigned k = (L & 127u) >> 1;
        aSrc[q] = A + (size_t)(rowBase + row) * K + chunk * 64 + k;
        aOff[q] = q * 8192u + (unsigned)wv * 1024u;
    }
    const ushort_t* bSrc[4];
    unsigned bOff[4];
    #pragma unroll
    for (int q = 0; q < 4; ++q) {
        unsigned P = q * 8192u + (unsigned)tid * 16u;
        unsigned L = swz64(P);
        bSrc[q] = Wt + (size_t)(L >> 7) * K + ((L & 127u) >> 1);
        bOff[q] = q * 8192u + (unsigned)wv * 1024u;
    }
    #pragma unroll
    for (int q = 0; q < 2; ++q) GLL(aSrc[q], (char*)sA + aOff[q]);
    #pragma unroll
    for (int q = 0; q < 4; ++q) GLL(bSrc[q], (char*)sB[0] + bOff[q]);

    if constexpr (EPI == 2) {
        int j = tid & 255, h = tid >> 8;
        if (h == 0) {
            int pb = (blockIdx.x >> 3) << 3;
            float s = 0.f;
            #pragma unroll
            for (int k2 = 0; k2 < 8; ++k2) s += partial[(size_t)(pb + k2) * C_ + j];
            sg[j] = s * (1.f / 256.f);
        }
        __syncthreads();
        float a2 = 0.f;
        #pragma unroll 8
        for (int c2 = h * 128; c2 < h * 128 + 128; ++c2)
            a2 = fmaf(sg[c2], w1[c2 * C_ + j], a2);
        sgp[h][j] = a2;
        __syncthreads();
        if (h == 0) sgv[j] = b1[j] + sgp[0][j] + sgp[1][j];
        __syncthreads();
    }

    unsigned oA[2][2], oB[2][2];
    #pragma unroll
    for (int mi = 0; mi < 2; ++mi)
        #pragma unroll
        for (int kk = 0; kk < 2; ++kk)
            oA[mi][kk] = swz64((unsigned)(((mi * 16 + l16) << 7) + (kk << 6) + (g << 4)));
    #pragma unroll
    for (int ni = 0; ni < 2; ++ni)
        #pragma unroll
        for (int kk = 0; kk < 2; ++kk)
            oB[ni][kk] = swz64((unsigned)(((wv * 32 + ni * 16 + l16) << 7) + (kk << 6) + (g << 4)));

    f32x4 acc[2][2] = {};
    int cur = 0;
    for (int t = 0; t < 4; ++t) {
        if (t < 3) {
            int o = (t + 1) << 6;
            #pragma unroll
            for (int q = 0; q < 4; ++q) GLL(bSrc[q] + o, (char*)sB[cur ^ 1] + bOff[q]);
            asm volatile("s_waitcnt vmcnt(4)" ::: "memory");
        } else {
            asm volatile("s_waitcnt vmcnt(0)" ::: "memory");
        }
        asm volatile("s_barrier" ::: "memory");
        const char* cA = (const char*)sA + t * 4096;
        const char* cB = (const char*)sB[cur];
        #pragma unroll
        for (int kk = 0; kk < 2; ++kk) {
            bf16x8 a0v = *(const bf16x8*)(cA + oA[0][kk]);
            bf16x8 a1v = *(const bf16x8*)(cA + oA[1][kk]);
            bf16x8 b0v = *(const bf16x8*)(cB + oB[0][kk]);
            bf16x8 b1v = *(const bf16x8*)(cB + oB[1][kk]);
            acc[0][0] = __builtin_amdgcn_mfma_f32_16x16x32_bf16(a0v, b0v, acc[0][0], 0, 0, 0);
            acc[0][1] = __builtin_amdgcn_mfma_f32_16x16x32_bf16(a0v, b1v, acc[0][1], 0, 0, 0);
            acc[1][0] = __builtin_amdgcn_mfma_f32_16x16x32_bf16(a1v, b0v, acc[1][0], 0, 0, 0);
            acc[1][1] = __builtin_amdgcn_mfma_f32_16x16x32_bf16(a1v, b1v, acc[1][1], 0, 0, 0);
        }
        asm volatile("s_barrier" ::: "memory");
        cur ^= 1;
    }

    float bv[2];
    #pragma unroll
    for (int ni = 0; ni < 2; ++ni) bv[ni] = bias[wv * 32 + ni * 16 + l16];
    #pragma unroll
    for (int mi = 0; mi < 2; ++mi)
        #pragma unroll
        for (int ni = 0; ni < 2; ++ni)
            #pragma unroll
            for (int j = 0; j < 4; ++j)
                acc[mi][ni][j] += bv[ni];

    if constexpr (EPI == 4) {
        #pragma unroll
        for (int mi = 0; mi < 2; ++mi)
            #pragma unroll
            for (int j = 0; j < 4; ++j) {
                float s = acc[mi][0][j] + acc[mi][1][j];
                float q = acc[mi][0][j] * acc[mi][0][j] + acc[mi][1][j] * acc[mi][1][j];
                #pragma unroll
                for (int off = 1; off < 16; off <<= 1) {
                    s += __shfl_xor(s, off);
                    q += __shfl_xor(q, off);
                }
                if (l16 == 0) {
                    int r = mi * 16 + g * 4 + j;
                    red[wv][r][0] = s;
                    red[wv][r][1] = q;
                }
            }
        __syncthreads();
        float colsum[2] = {0.f, 0.f};
        #pragma unroll
        for (int mi = 0; mi < 2; ++mi)
            #pragma unroll
            for (int j = 0; j < 4; ++j) {
                int r = mi * 16 + g * 4 + j;
                float sum = 0.f, sq = 0.f;
                #pragma unroll
                for (int w = 0; w < 8; ++w) { sum += red[w][r][0]; sq += red[w][r][1]; }
                float mu = sum * (1.f / 256.f);
                float var = fmaxf(sq * (1.f / 256.f) - mu * mu, 0.f);
                float rs = rsqrtf(var + 1e-6f);
                int row = rowBase + r;
                #pragma unroll
                for (int ni = 0; ni < 2; ++ni) {
                    int col = wv * 32 + ni * 16 + l16;
                    size_t idx = (size_t)row * C_ + col;
                    float o = residf[idx] + (acc[mi][ni][j] - mu) * rs * p0[col] + p1[col];
                    Cb[idx] = f2bf(o);
                    colsum[ni] += o;
                }
            }
        #pragma unroll
        for (int ni = 0; ni < 2; ++ni) {
            float s = colsum[ni];
            s += __shfl_xor(s, 16);
            s += __shfl_xor(s, 32);
            if (g == 0) partial[(size_t)blockIdx.x * C_ + wv * 32 + ni * 16 + l16] = s;
        }
    } else {  // EPI == 2
        #pragma unroll
        for (int ni = 0; ni < 2; ++ni) {
            int col = wv * 32 + ni * 16 + l16;
            float gv = sgv[col];
            float s0v = p0[col], h0v = p1[col], s1v = p2[col], h1v = p3[col];
            #pragma unroll
            for (int mi = 0; mi < 2; ++mi)
                #pragma unroll
                for (int j = 0; j < 4; ++j) {
                    int row = rowBase + mi * 16 + g * 4 + j;
                    size_t idx = (size_t)row * C_ + col;
                    float v = acc[mi][ni][j] + gv;
                    v = v * s0v + h0v;
                    float o = (bf2f(residb[idx]) + v) * s1v + h1v;
                    Cb[idx] = f2bf(o);
                }
        }
    }
}

// ------ FF GEMM: 512 thr / 8 waves (4x2), BM=128, BN(128|64), BK=64, dbuf -----
// grid = (rowChunks, colChunks): all col-chunks of a row-panel -> same XCD (r%8)
template <int EPI, int BN>
__global__ __launch_bounds__(512) void k_gemm128(
    const ushort_t* __restrict__ A, const ushort_t* __restrict__ Wt,
    const float* __restrict__ bias, int K, int Nn,
    ushort_t* __restrict__ Cb, float* __restrict__ Cf,
    const ushort_t* __restrict__ residb,
    const float* __restrict__ p0, const float* __restrict__ p1) {
    const int NI = BN / 32;
    const int QB = (BN == 128) ? 2 : 1;
    __shared__ __align__(16) ushort_t sA[2][8192];
    __shared__ __align__(16) ushort_t sB[2][BN * 64];
    int tid = threadIdx.x;
    int lane = tid & 63, wv = tid >> 6;
    int rowBase = blockIdx.x * 128, colBase = blockIdx.y * BN;
    int l16 = lane & 15, g = (lane >> 4) & 3;
    int wr = (wv >> 1) * 32, wc = (wv & 1) * (BN / 2);

    const ushort_t* aSrc[2];
    unsigned aOff[2];
    #pragma unroll
    for (int q = 0; q < 2; ++q) {
        unsigned P = q * 8192u + (unsigned)tid * 16u;
        unsigned L = swz64(P);
        aSrc[q] = A + (size_t)(rowBase + (L >> 7)) * K + ((L & 127u) >> 1);
        aOff[q] = q * 8192u + (unsigned)wv * 1024u;
    }
    const ushort_t* bSrc[QB];
    unsigned bOff[QB];
    #pragma unroll
    for (int q = 0; q < QB; ++q) {
        unsigned P = q * 8192u + (unsigned)tid * 16u;
        unsigned L = swz64(P);
        bSrc[q] = Wt + (size_t)(colBase + (L >> 7)) * K + ((L & 127u) >> 1);
        bOff[q] = q * 8192u + (unsigned)wv * 1024u;
    }

    unsigned oA[2][2], oB[NI][2];
    #pragma unroll
    for (int mi = 0; mi < 2; ++mi)
        #pragma unroll
        for (int kk = 0; kk < 2; ++kk)
            oA[mi][kk] = swz64((unsigned)(((wr + mi * 16 + l16) << 7) + (kk << 6) + (g << 4)));
    #pragma unroll
    for (int ni = 0; ni < NI; ++ni)
        #pragma unroll
        for (int kk = 0; kk < 2; ++kk)
            oB[ni][kk] = swz64((unsigned)(((wc + ni * 16 + l16) << 7) + (kk << 6) + (g << 4)));

    f32x4 acc[2][NI] = {};
    int nt = K >> 6;

    #pragma unroll
    for (int q = 0; q < 2; ++q) GLL(aSrc[q], (char*)sA[0] + aOff[q]);
    #pragma unroll
    for (int q = 0; q < QB; ++q) GLL(bSrc[q], (char*)sB[0] + bOff[q]);

    int cur = 0;
    for (int t = 0; t < nt; ++t) {
        if (t + 1 < nt) {
            int o = (t + 1) << 6;
            #pragma unroll
            for (int q = 0; q < 2; ++q) GLL(aSrc[q] + o, (char*)sA[cur ^ 1] + aOff[q]);
            #pragma unroll
            for (int q = 0; q < QB; ++q) GLL(bSrc[q] + o, (char*)sB[cur ^ 1] + bOff[q]);
            if constexpr (BN == 128) asm volatile("s_waitcnt vmcnt(4)" ::: "memory");
            else                     asm volatile("s_waitcnt vmcnt(3)" ::: "memory");
        } else {
            asm volatile("s_waitcnt vmcnt(0)" ::: "memory");
        }
        asm volatile("s_barrier" ::: "memory");
        const char* cA = (const char*)sA[cur];
        const char* cB = (const char*)sB[cur];
        #pragma unroll
        for (int kk = 0; kk < 2; ++kk) {
            bf16x8 af[2], bff[NI];
            #pragma unroll
            for (int mi = 0; mi < 2; ++mi) af[mi] = *(const bf16x8*)(cA + oA[mi][kk]);
            #pragma unroll
            for (int ni = 0; ni < NI; ++ni) bff[ni] = *(const bf16x8*)(cB + oB[ni][kk]);
            #pragma unroll
            for (int mi = 0; mi < 2; ++mi)
                #pragma unroll
                for (int ni = 0; ni < NI; ++ni)
                    acc[mi][ni] = __builtin_amdgcn_mfma_f32_16x16x32_bf16(af[mi], bff[ni], acc[mi][ni], 0, 0, 0);
        }
        asm volatile("s_barrier" ::: "memory");
        cur ^= 1;
    }

    #pragma unroll
    for (int ni = 0; ni < NI; ++ni) {
        int col = colBase + wc + ni * 16 + l16;
        float bvv = bias[col];
        float s0v = 0.f, h0v = 0.f;
        if constexpr (EPI == 3) { s0v = p0[col]; h0v = p1[col]; }
        #pragma unroll
        for (int mi = 0; mi < 2; ++mi)
            #pragma unroll
            for (int j = 0; j < 4; ++j) {
                int row = rowBase + wr + mi * 16 + g * 4 + j;
                size_t idx = (size_t)row * Nn + col;
                float v = acc[mi][ni][j] + bvv;
                if constexpr (EPI == 1) {
                    Cb[idx] = f2bf(fmaxf(v, 0.f));
                } else {
                    Cf[idx] = (bf2f(residb[idx]) + v) * s0v + h0v;
                }
            }
    }
}

extern "C" void kernel_launch(void* const* d_in, const int* in_sizes, int n_in,
                              void* d_out, int out_size, void* d_ws, size_t ws_size,
                              hipStream_t stream) {
    const float* x      = (const float*)d_in[0];
    const float* coords = (const float*)d_in[1];
    const float* dwk    = (const float*)d_in[2];
    const float* dwb    = (const float*)d_in[3];
    const float* pw_w   = (const float*)d_in[4];
    const float* pw_b   = (const float*)d_in[5];
    const float* ln_g   = (const float*)d_in[6];
    const float* ln_b   = (const float*)d_in[7];
    const float* gi_w1  = (const float*)d_in[8];
    const float* gi_b1  = (const float*)d_in[9];
    const float* gi_w2  = (const float*)d_in[10];
    const float* gi_b2  = (const float*)d_in[11];
    const float* bn0g = (const float*)d_in[12], *bn0b = (const float*)d_in[13];
    const float* bn0m = (const float*)d_in[14], *bn0v = (const float*)d_in[15];
    const float* bn1g = (const float*)d_in[16], *bn1b = (const float*)d_in[17];
    const float* bn1m = (const float*)d_in[18], *bn1v = (const float*)d_in[19];
    const float* bn2g = (const float*)d_in[20], *bn2b = (const float*)d_in[21];
    const float* bn2m = (const float*)d_in[22], *bn2v = (const float*)d_in[23];
    const float* w_ff1 = (const float*)d_in[24];
    const float* b_ff1 = (const float*)d_in[25];
    const float* w_ff2 = (const float*)d_in[26];
    const float* b_ff2 = (const float*)d_in[27];

    char* ws = (char*)d_ws;
    int*      ncnt    = (int*)(ws + 0);             // 32 KB
    float*    bnsh    = (float*)(ws + 32768);       // 6 KB
    float*    partial = (float*)(ws + 40960);       // 256 KB
    ushort_t* WtPW    = (ushort_t*)(ws + 303104);   // 128 KB
    ushort_t* WtGI    = (ushort_t*)(ws + 434176);   // 128 KB
    ushort_t* WtF1    = (ushort_t*)(ws + 565248);   // 512 KB
    ushort_t* WtF2    = (ushort_t*)(ws + 1089536);  // 512 KB
    ushort_t* nbr     = (ushort_t*)(ws + 1613824);  // 4 MB
    ushort_t* x1b     = (ushort_t*)(ws + 5808128);  // 4 MB
    ushort_t* x2b     = (ushort_t*)(ws + 10002432); // 4 MB
    ushort_t* t0      = (ushort_t*)(ws + 14196736); // 4 MB
    ushort_t* u_b     = (ushort_t*)(ws + 18391040); // 16 MB
    float*    outx    = (float*)d_out;

    const int M = B_ * N_;  // 8192

    // 1) geo + bnprep + coords passthrough (33 blocks — short critical path)
    k_geo<<<B_ + 1, N_, 0, stream>>>(
        coords, nbr, ncnt,
        bn0g, bn0b, bn0m, bn0v, bn1g, bn1b, bn1m, bn1v, bn2g, bn2b, bn2m, bn2v,
        bnsh, outx + (size_t)M * C_);

    // 2) CPE (2048 blocks, XCD-chunked) + weight transpose (640 blocks)
    k_cpw<<<2048 + 640, 256, 0, stream>>>(
        x, nbr, ncnt, dwk, dwb, t0,
        pw_w, gi_w2, w_ff1, w_ff2, WtPW, WtGI, WtF1, WtF2);

    // 3) x1 = x + LN(t0@pw_w + pw_b) -> x1b; colsum partials (8-wave)
    k_gemmrow8<4><<<M / 32, 512, 0, stream>>>(
        t0, WtPW, pw_b, x1b, x, nullptr,
        ln_g, ln_b, nullptr, nullptr,
        partial, nullptr, nullptr);

    // 4) x2 = bn1(x1 + bn0(x1@gi_w2 + gi_b2 + gvec)) -> x2b (8-wave)
    k_gemmrow8<2><<<M / 32, 512, 0, stream>>>(
        x1b, WtGI, gi_b2, x2b, nullptr, x1b,
        bnsh, bnsh + 256, bnsh + 512, bnsh + 768,
        partial, gi_w1, gi_b1);

    // 5) u = relu(x2 @ w_ff1 + b_ff1)   (512 thr, 8 waves)
    k_gemm128<1, 128><<<dim3(M / 128, DFF_ / 128), 512, 0, stream>>>(
        x2b, WtF1, b_ff1, C_, DFF_, u_b, nullptr, nullptr, nullptr, nullptr);

    // 6) out = bn2(x2 + u @ w_ff2 + b_ff2)   (512 thr, 8 waves)
    k_gemm128<3, 64><<<dim3(M / 128, C_ / 64), 512, 0, stream>>>(
        u_b, WtF2, b_ff2, DFF_, C_, nullptr, outx, x2b,
        bnsh + 1024, bnsh + 1280);
}